// Round 2
// baseline (251.014 us; speedup 1.0000x reference)
//
#include <hip/hip_runtime.h>

#define NB 8
#define NN 2048
#define DIN 256
#define HID 64
#define JSPLIT 8

typedef _Float16 f16x8_t __attribute__((ext_vector_type(8)));
typedef _Float16 f16x2_t __attribute__((ext_vector_type(2)));
typedef _Float16 f16x4_t __attribute__((ext_vector_type(4)));
typedef float f32x16_t __attribute__((ext_vector_type(16)));

// order-preserving float<->uint for atomicMax over signed floats
__device__ __forceinline__ unsigned int fenc(float f) {
    unsigned int u = __float_as_uint(f);
    return (u & 0x80000000u) ? ~u : (u | 0x80000000u);
}
__device__ __forceinline__ float fdec(unsigned int u) {
    return (u & 0x80000000u) ? __uint_as_float(u & 0x7fffffffu)
                             : __uint_as_float(~u);
}

// ---------------------------------------------------------------------------
// k_pack: adjacency -> 64-bit masks via wave ballot.  OWN kernel (no LDS!):
// in r0 this ran inside a 64KB-LDS kernel -> 2 blocks/CU -> 2 waves/SIMD for
// the 134 MB stream. Standalone it gets 8 blocks/CU and is cleanly BW-bound.
// Also initializes the f2max atomic slots (k_pack fully precedes k_wh).
// ---------------------------------------------------------------------------
__global__ __launch_bounds__(256) void k_pack(
    const int* __restrict__ adj, unsigned long long* __restrict__ mb,
    unsigned int* __restrict__ f2mxu)
{
    if (blockIdx.x == 0 && threadIdx.x < NB) f2mxu[threadIdx.x] = 0u;
    const int lane = threadIdx.x & 63;
    const int wave = blockIdx.x * 4 + (threadIdx.x >> 6);   // 0..8191
#pragma unroll
    for (int rr = 0; rr < 2; ++rr) {
        const int row = wave * 2 + rr;                      // 0..16383 (= b*NN+n)
        const int* ar = adj + (size_t)row * NN;
        unsigned long long myw = 0;
#pragma unroll
        for (int k = 0; k < 32; ++k) {
            unsigned long long bal = __ballot(ar[k * 64 + lane] != 0);
            if ((lane & 31) == k) myw = bal;
        }
        if (lane < 32) mb[(size_t)row * 32 + lane] = myw;
    }
}

// ---------------------------------------------------------------------------
// k_wh: Wh = x@W fp32, f1/f2, WhT fp16 [b][h][n], fused per-batch f2-max
// (ordered-uint atomicMax replaces the separate k_f2max kernel).
// ---------------------------------------------------------------------------
__global__ __launch_bounds__(256) void k_wh(
    const float* __restrict__ x, const float* __restrict__ W,
    const float* __restrict__ a, _Float16* __restrict__ wht,
    float* __restrict__ f1, float* __restrict__ f2,
    unsigned int* __restrict__ f2mxu)
{
    __shared__ float smem[DIN * 64];   // 64 KB (reused as T[h][row])
    const int bid = blockIdx.x;
    const int t = threadIdx.x;

    const int g0 = bid * 64;           // global row base (over B*N)
    const int b = g0 >> 11;
    const int n0 = g0 & (NN - 1);

    const float4* x4 = (const float4*)x;
#pragma unroll
    for (int it = 0; it < 16; ++it) {
        int c = t + it * 256;
        int row = c & 63;
        int dg = c >> 6;
        float4 v = x4[(size_t)(g0 + row) * 64 + dg];
        smem[(dg * 4 + 0) * 64 + row] = v.x;
        smem[(dg * 4 + 1) * 64 + row] = v.y;
        smem[(dg * 4 + 2) * 64 + row] = v.z;
        smem[(dg * 4 + 3) * 64 + row] = v.w;
    }
    __syncthreads();

    const int hq = t & 15;   // h-quad: cols hq*4..+3
    const int rg = t >> 4;   // row-group: rows rg*4..+3
    const float4* W4 = (const float4*)W;
    float acc[4][4] = {};
#pragma unroll 8
    for (int d = 0; d < DIN; ++d) {
        float4 wv = W4[d * 16 + hq];
        float4 xv = *(const float4*)&smem[d * 64 + rg * 4];
        float xr[4] = {xv.x, xv.y, xv.z, xv.w};
        float wk[4] = {wv.x, wv.y, wv.z, wv.w};
#pragma unroll
        for (int r = 0; r < 4; ++r)
#pragma unroll
            for (int k = 0; k < 4; ++k) acc[r][k] += xr[r] * wk[k];
    }

    // f1/f2: reduce over h (16 hq-lanes per row-group; xor<16 stays in group)
    float4 a1v = ((const float4*)a)[hq];
    float4 a2v = ((const float4*)a)[16 + hq];
    float mx2 = -3.4e38f;
#pragma unroll
    for (int r = 0; r < 4; ++r) {
        float p1 = acc[r][0] * a1v.x + acc[r][1] * a1v.y + acc[r][2] * a1v.z + acc[r][3] * a1v.w;
        float p2 = acc[r][0] * a2v.x + acc[r][1] * a2v.y + acc[r][2] * a2v.z + acc[r][3] * a2v.w;
#pragma unroll
        for (int m = 1; m < 16; m <<= 1) {
            p1 += __shfl_xor(p1, m);
            p2 += __shfl_xor(p2, m);
        }
        if (hq == 0) {
            f1[g0 + rg * 4 + r] = p1;
            f2[g0 + rg * 4 + r] = p2;
        }
        mx2 = fmaxf(mx2, p2);
    }
    // wave max (rg spans 2 bits inside a wave; p2 equal across hq lanes)
    mx2 = fmaxf(mx2, __shfl_xor(mx2, 16));
    mx2 = fmaxf(mx2, __shfl_xor(mx2, 32));
    if ((t & 63) == 0) smem[8192 + (t >> 6)] = mx2;   // x-staging region is dead here

    __syncthreads();
    if (t == 0) {
        float m4 = fmaxf(fmaxf(smem[8192], smem[8193]), fmaxf(smem[8194], smem[8195]));
        atomicMax(&f2mxu[b], fenc(m4));
    }
    // transpose: T[h][row], 4-row groups XOR-swizzled to break bank conflicts
    // (writes land in smem[0..4095], no overlap with smem[8192..8195] reads)
#pragma unroll
    for (int r = 0; r < 4; ++r)
#pragma unroll
        for (int k = 0; k < 4; ++k) {
            int h = hq * 4 + k;
            int row = rg * 4 + r;
            smem[h * 64 + (((row >> 2) ^ (h & 15)) << 2) + (row & 3)] = acc[r][k];
        }
    __syncthreads();

    const int h = t >> 2;    // 0..63
    const int rc = t & 3;    // 16-row chunk
    union { _Float16 fh[16]; uint4 u4[2]; } uh;
#pragma unroll
    for (int q = 0; q < 4; ++q) {
        float4 v = *(const float4*)&smem[h * 64 + (((rc * 4 + q) ^ (h & 15)) << 2)];
        uh.fh[q * 4 + 0] = (_Float16)v.x;
        uh.fh[q * 4 + 1] = (_Float16)v.y;
        uh.fh[q * 4 + 2] = (_Float16)v.z;
        uh.fh[q * 4 + 3] = (_Float16)v.w;
    }
    size_t obase = (size_t)(b * HID + h) * NN + n0 + rc * 16;
    *(uint4*)&wht[obase] = uh.u4[0];
    *(uint4*)&wht[obase + 8] = uh.u4[1];
}

// ---------------------------------------------------------------------------
// k3: masked-softmax + P@Wh via fp16 32x32x16 MFMA (mask-word form, as r0).
// Z_i computed on the MFMA pipe: acc2 = P @ ones.
// ---------------------------------------------------------------------------
__global__ __launch_bounds__(256, 4) void k_attn(
    const unsigned long long* __restrict__ mb, const _Float16* __restrict__ wht,
    const float* __restrict__ f1, const float* __restrict__ f2,
    const unsigned int* __restrict__ f2mxu,
    _Float16* __restrict__ accp, float* __restrict__ zp)
{
    __shared__ _Float16 whx[64 * 128];   // [h][j128], 8-elem groups XOR-swizzled
    const int t = threadIdx.x;
    const int w = t >> 6, lane = t & 63;
    const int bx = blockIdx.x;
    const int js = bx & 7;
    const int it = (bx >> 3) & 15;
    const int b = bx >> 7;
    const int I0 = it * 128 + w * 32;
    const int half = lane >> 5;
    const int m32 = lane & 31;
    const int row = I0 + m32;
    const int jb0 = js * 256;

    const float f1v = f1[b * NN + row];
    float Mi = f1v + fdec(f2mxu[b]);
    Mi = Mi > 0.f ? Mi : 0.2f * Mi;            // lrelu monotone -> valid bound
    const float LOG2E = 1.4426950408889634f;
    const float negMiL = -Mi * LOG2E;
    const float* f2p = f2 + b * NN;

    // this row's 4 mask words (j in [jb0, jb0+256))
    const unsigned long long* mrow = mb + (size_t)(b * NN + row) * 32 + js * 4;
    unsigned long long m[4];
    {
        ulonglong2 q0 = *(const ulonglong2*)mrow;
        ulonglong2 q1 = *(const ulonglong2*)(mrow + 2);
        m[0] = q0.x; m[1] = q0.y; m[2] = q1.x; m[3] = q1.y;
    }

    f16x8_t bones;
#pragma unroll
    for (int i = 0; i < 8; ++i) bones[i] = (_Float16)1.0f;

    f32x16_t acc0, acc1, acc2;
#pragma unroll
    for (int i = 0; i < 16; ++i) { acc0[i] = 0.f; acc1[i] = 0.f; acc2[i] = 0.f; }

#pragma unroll
    for (int stg = 0; stg < 2; ++stg) {
        const int jt = jb0 + stg * 128;
        if (stg) __syncthreads();
#pragma unroll
        for (int cc = 0; cc < 4; ++cc) {
            int c = t + cc * 256;
            int h = c >> 4, g = c & 15;
            int gp = g ^ (h & 15);
            size_t src = (size_t)(b * HID + h) * NN + jt + g * 8;
            *(uint4*)&whx[h * 128 + gp * 8] = *(const uint4*)&wht[src];
        }
        __syncthreads();
#pragma unroll
        for (int s8 = 0; s8 < 8; ++s8) {
            const int jl = jt + s8 * 16 + half * 8;   // this lane's 8-j group
            const uint32_t bits8 =
                (uint32_t)(m[stg * 2 + (s8 >> 2)] >> (((s8 & 3) * 16) + half * 8)) & 0xffu;
            float4 fa = *(const float4*)&f2p[jl];
            float4 fb = *(const float4*)&f2p[jl + 4];
            float fv[8] = {fa.x, fa.y, fa.z, fa.w, fb.x, fb.y, fb.z, fb.w};
            union { f16x2_t h2[4]; f16x8_t v; } ua;
#pragma unroll
            for (int jp = 0; jp < 4; ++jp) {
                float pv[2];
#pragma unroll
                for (int e = 0; e < 2; ++e) {
                    int jj = jp * 2 + e;
                    float t1 = f1v + fv[jj];
                    t1 = fmaxf(t1, 0.2f * t1);
                    pv[e] = (bits8 & (1u << jj))
                          ? __builtin_amdgcn_exp2f(fmaf(t1, LOG2E, negMiL))
                          : 0.f;
                }
                auto pk = __builtin_amdgcn_cvt_pkrtz(pv[0], pv[1]);  // __fp16x2
                ua.h2[jp] = *(f16x2_t*)&pk;                          // bit-pun
            }
            const int gx = (2 * s8 + half) ^ (m32 & 15);
            f16x8_t b0 = *(const f16x8_t*)&whx[m32 * 128 + (gx << 3)];
            f16x8_t b1 = *(const f16x8_t*)&whx[(m32 + 32) * 128 + (gx << 3)];
            acc0 = __builtin_amdgcn_mfma_f32_32x32x16_f16(ua.v, b0, acc0, 0, 0, 0);
            acc1 = __builtin_amdgcn_mfma_f32_32x32x16_f16(ua.v, b1, acc1, 0, 0, 0);
            acc2 = __builtin_amdgcn_mfma_f32_32x32x16_f16(ua.v, bones, acc2, 0, 0, 0);
        }
    }

    // epilogue: zp from acc2 (all columns equal; col-0 lanes write),
    // fp16 partials for the numerator.
    float* zb = zp + (size_t)(js * NB + b) * NN;
    _Float16* ap = accp + (size_t)(js * NB + b) * NN * HID;
#pragma unroll
    for (int r = 0; r < 16; ++r) {
        int rr = (r & 3) + 8 * (r >> 2) + 4 * half;   // verified C-layout (m74/m101)
        if (m32 == 0) zb[I0 + rr] = acc2[r];
        ap[(size_t)(I0 + rr) * HID + m32] = (_Float16)acc0[r];
        ap[(size_t)(I0 + rr) * HID + m32 + 32] = (_Float16)acc1[r];
    }
}

// ---------------------------------------------------------------------------
// k4: out = (sum_js acc_js) / (sum_js Z_js)   (fp16 partials, fp32 combine)
// ---------------------------------------------------------------------------
__global__ __launch_bounds__(256) void k_combine(
    const _Float16* __restrict__ accp, const float* __restrict__ zp,
    float* __restrict__ out)
{
    int gid = blockIdx.x * 256 + threadIdx.x;   // 0..262143 (4-h granules)
    int h4 = gid & 15;
    int rowg = gid >> 4;                        // b*N + n
    float z = 0.f;
    float s0 = 0.f, s1 = 0.f, s2 = 0.f, s3 = 0.f;
#pragma unroll
    for (int js = 0; js < JSPLIT; ++js) {
        size_t base = (size_t)js * NB * NN;
        z += zp[base + rowg];
        f16x4_t v = *(const f16x4_t*)&accp[(base + rowg) * HID + h4 * 4];
        s0 += (float)v[0]; s1 += (float)v[1]; s2 += (float)v[2]; s3 += (float)v[3];
    }
    float zi = 1.f / z;
    float4 o = {s0 * zi, s1 * zi, s2 * zi, s3 * zi};
    ((float4*)out)[gid] = o;
}

extern "C" void kernel_launch(void* const* d_in, const int* in_sizes, int n_in,
                              void* d_out, int out_size, void* d_ws, size_t ws_size,
                              hipStream_t stream)
{
    const float* x = (const float*)d_in[0];
    const int* adj = (const int*)d_in[1];
    const float* W = (const float*)d_in[2];
    const float* a = (const float*)d_in[3];
    float* out = (float*)d_out;
    char* ws = (char*)d_ws;

    _Float16* wht = (_Float16*)(ws);                              // 2 MB
    float* f1   = (float*)(ws + (2u << 20));                      // 64 KB
    float* f2   = (float*)(ws + (2u << 20) + (64u << 10));        // 64 KB
    unsigned int* f2mxu = (unsigned int*)(ws + (2u << 20) + (128u << 10)); // 32 B
    unsigned long long* mbuf = (unsigned long long*)(ws + (3u << 20)); // 4 MB
    _Float16* accp = (_Float16*)(ws + (8u << 20));                // 16 MB
    float* zp   = (float*)(ws + (24u << 20));                     // 512 KB

    hipLaunchKernelGGL(k_pack, dim3(2048), dim3(256), 0, stream, adj, mbuf, f2mxu);
    hipLaunchKernelGGL(k_wh, dim3(256), dim3(256), 0, stream, x, W, a, wht, f1, f2, f2mxu);
    hipLaunchKernelGGL(k_attn, dim3(1024), dim3(256), 0, stream, mbuf, wht, f1, f2, f2mxu, accp, zp);
    hipLaunchKernelGGL(k_combine, dim3(1024), dim3(256), 0, stream, accp, zp, out);
}

// Round 3
// 231.439 us; speedup vs baseline: 1.0846x; 1.0846x over previous
//
#include <hip/hip_runtime.h>

#define NB 8
#define NN 2048
#define DIN 256
#define HID 64

typedef _Float16 f16x8_t __attribute__((ext_vector_type(8)));
typedef _Float16 f16x2_t __attribute__((ext_vector_type(2)));
typedef float f32x16_t __attribute__((ext_vector_type(16)));

// ---------------------------------------------------------------------------
// k_prep: fused (wh-role | pack-role) — identical to the 227 µs baseline.
//   blocks 0..255   : Wh = x@W fp32, f1/f2, WhT fp16 [b][h][n]  (wh-role)
//   blocks 256..2303: adjacency -> 64-bit masks via wave ballot (pack-role)
// Pack is BW-bound even at 2 waves/SIMD (32 coalesced loads in flight/wave);
// fusing lets the adj stream overlap the wh compute.
// ---------------------------------------------------------------------------
__global__ __launch_bounds__(256) void k_prep(
    const float* __restrict__ x, const float* __restrict__ W,
    const float* __restrict__ a, const int* __restrict__ adj,
    unsigned long long* __restrict__ mb, _Float16* __restrict__ wht,
    float* __restrict__ f1, float* __restrict__ f2)
{
    __shared__ float smem[DIN * 64];   // 64 KB (wh-role only; reused as T[h][row])
    const int bid = blockIdx.x;
    const int t = threadIdx.x;

    if (bid >= 256) {
        // ---------------- pack-role ----------------
        const int lane = t & 63;
        const int wave = (bid - 256) * 4 + (t >> 6);   // 0..8191
#pragma unroll
        for (int rr = 0; rr < 2; ++rr) {
            const int row = wave * 2 + rr;             // 0..16383 (= b*NN+n)
            const int* ar = adj + (size_t)row * NN;
            unsigned long long myw = 0;
#pragma unroll
            for (int k = 0; k < 32; ++k) {
                unsigned long long bal = __ballot(ar[k * 64 + lane] != 0);
                if ((lane & 31) == k) myw = bal;
            }
            if (lane < 32) mb[(size_t)row * 32 + lane] = myw;
        }
        return;
    }

    // ---------------- wh-role ----------------
    const int g0 = bid * 64;           // global row base (over B*N)
    const int b = g0 >> 11;
    const int n0 = g0 & (NN - 1);

    const float4* x4 = (const float4*)x;
#pragma unroll
    for (int it = 0; it < 16; ++it) {
        int c = t + it * 256;
        int row = c & 63;
        int dg = c >> 6;
        float4 v = x4[(size_t)(g0 + row) * 64 + dg];
        smem[(dg * 4 + 0) * 64 + row] = v.x;
        smem[(dg * 4 + 1) * 64 + row] = v.y;
        smem[(dg * 4 + 2) * 64 + row] = v.z;
        smem[(dg * 4 + 3) * 64 + row] = v.w;
    }
    __syncthreads();

    const int hq = t & 15;   // h-quad: cols hq*4..+3
    const int rg = t >> 4;   // row-group: rows rg*4..+3
    const float4* W4 = (const float4*)W;
    float acc[4][4] = {};
#pragma unroll 8
    for (int d = 0; d < DIN; ++d) {
        float4 wv = W4[d * 16 + hq];
        float4 xv = *(const float4*)&smem[d * 64 + rg * 4];
        float xr[4] = {xv.x, xv.y, xv.z, xv.w};
        float wk[4] = {wv.x, wv.y, wv.z, wv.w};
#pragma unroll
        for (int r = 0; r < 4; ++r)
#pragma unroll
            for (int k = 0; k < 4; ++k) acc[r][k] += xr[r] * wk[k];
    }

    // f1/f2: reduce over h (16 hq-lanes per row-group; xor<16 stays in group)
    float4 a1v = ((const float4*)a)[hq];
    float4 a2v = ((const float4*)a)[16 + hq];
#pragma unroll
    for (int r = 0; r < 4; ++r) {
        float p1 = acc[r][0] * a1v.x + acc[r][1] * a1v.y + acc[r][2] * a1v.z + acc[r][3] * a1v.w;
        float p2 = acc[r][0] * a2v.x + acc[r][1] * a2v.y + acc[r][2] * a2v.z + acc[r][3] * a2v.w;
#pragma unroll
        for (int m = 1; m < 16; m <<= 1) {
            p1 += __shfl_xor(p1, m);
            p2 += __shfl_xor(p2, m);
        }
        if (hq == 0) {
            f1[g0 + rg * 4 + r] = p1;
            f2[g0 + rg * 4 + r] = p2;
        }
    }

    __syncthreads();
    // transpose: T[h][row], 4-row groups XOR-swizzled to break bank conflicts
#pragma unroll
    for (int r = 0; r < 4; ++r)
#pragma unroll
        for (int k = 0; k < 4; ++k) {
            int h = hq * 4 + k;
            int row = rg * 4 + r;
            smem[h * 64 + (((row >> 2) ^ (h & 15)) << 2) + (row & 3)] = acc[r][k];
        }
    __syncthreads();

    const int h = t >> 2;    // 0..63
    const int rc = t & 3;    // 16-row chunk
    union { _Float16 fh[16]; uint4 u4[2]; } uh;
#pragma unroll
    for (int q = 0; q < 4; ++q) {
        float4 v = *(const float4*)&smem[h * 64 + (((rc * 4 + q) ^ (h & 15)) << 2)];
        uh.fh[q * 4 + 0] = (_Float16)v.x;
        uh.fh[q * 4 + 1] = (_Float16)v.y;
        uh.fh[q * 4 + 2] = (_Float16)v.z;
        uh.fh[q * 4 + 3] = (_Float16)v.w;
    }
    size_t obase = (size_t)(b * HID + h) * NN + n0 + rc * 16;
    *(uint4*)&wht[obase] = uh.u4[0];
    *(uint4*)&wht[obase + 8] = uh.u4[1];
}

// ---------------------------------------------------------------------------
// k2: f2max[b] = max_n f2[b][n]  (feeds the softmax shift bound)
// ---------------------------------------------------------------------------
__global__ __launch_bounds__(256) void k_f2max(
    const float* __restrict__ f2, float* __restrict__ f2mx)
{
    __shared__ float red[4];
    const int b = blockIdx.x, t = threadIdx.x;
    float m = -3.4e38f;
    for (int i = t; i < NN; i += 256) m = fmaxf(m, f2[b * NN + i]);
#pragma unroll
    for (int s = 1; s < 64; s <<= 1) m = fmaxf(m, __shfl_xor(m, s));
    if ((t & 63) == 0) red[t >> 6] = m;
    __syncthreads();
    if (t == 0) f2mx[b] = fmaxf(fmaxf(red[0], red[1]), fmaxf(red[2], red[3]));
}

// ---------------------------------------------------------------------------
// k3: masked-softmax + P@Wh, FULL J per block (no split-K partials!).
// 512 blocks = (b, 32-row tile). 4 waves; wave w owns j-quarter [w*512,+512).
// Per sync round: stage 4x128-j Wh chunks (64 KB LDS), each wave runs 8
// MFMA steps on its slab. End: 4-way partial combine in LDS, single divide,
// direct fp32 out write. Removes accp/zp round-trip (32 MB) + k_combine.
// Z on the MFMA pipe: acc2 = P @ ones (sums exactly the quantized fp16 p).
// ---------------------------------------------------------------------------
__global__ __launch_bounds__(256) void k_attn(
    const unsigned long long* __restrict__ mb, const _Float16* __restrict__ wht,
    const float* __restrict__ f1, const float* __restrict__ f2,
    const float* __restrict__ f2mx,
    float* __restrict__ out)
{
    __shared__ _Float16 whx[4 * 64 * 128];   // 64 KB: [slab][h][j128], XOR-swizzled
    const int t = threadIdx.x;
    const int w = t >> 6, lane = t & 63;
    const int bx = blockIdx.x;
    const int it = bx & 63;
    const int b = bx >> 6;
    const int I0 = it * 32;
    const int half = lane >> 5;
    const int m32 = lane & 31;
    const int row = I0 + m32;
    const int jq0 = w * 512;           // this wave's j-quarter base

    const float f1v = f1[b * NN + row];
    float Mi = f1v + f2mx[b];
    Mi = Mi > 0.f ? Mi : 0.2f * Mi;            // lrelu monotone -> valid bound
    const float LOG2E = 1.4426950408889634f;
    const float negMiL = -Mi * LOG2E;
    const float* f2p = f2 + b * NN;

    // this row's 8 mask words (j in [jq0, jq0+512))
    const unsigned long long* mrow = mb + (size_t)(b * NN + row) * 32 + w * 8;
    unsigned long long m[8];
#pragma unroll
    for (int q = 0; q < 4; ++q) {
        ulonglong2 qq = *(const ulonglong2*)(mrow + q * 2);
        m[q * 2] = qq.x; m[q * 2 + 1] = qq.y;
    }

    f16x8_t bones;
#pragma unroll
    for (int i = 0; i < 8; ++i) bones[i] = (_Float16)1.0f;

    f32x16_t acc0, acc1, acc2;
#pragma unroll
    for (int i = 0; i < 16; ++i) { acc0[i] = 0.f; acc1[i] = 0.f; acc2[i] = 0.f; }

    for (int s = 0; s < 4; ++s) {
        if (s) __syncthreads();
        // stage: 4 slabs x 64 h x 128 j  (64 KB), coalesced uint4
#pragma unroll
        for (int cc = 0; cc < 16; ++cc) {
            int id = t + cc * 256;
            int g = id & 15;
            int h = (id >> 4) & 63;
            int slab = id >> 10;
            int gp = g ^ (h & 15);
            size_t src = (size_t)(b * HID + h) * NN + slab * 512 + s * 128 + g * 8;
            *(uint4*)&whx[slab * 8192 + h * 128 + gp * 8] = *(const uint4*)&wht[src];
        }
        __syncthreads();
#pragma unroll
        for (int s8 = 0; s8 < 8; ++s8) {
            const int jl = jq0 + s * 128 + s8 * 16 + half * 8;   // lane's 8-j group
            const uint32_t bits8 =
                (uint32_t)(m[s * 2 + (s8 >> 2)] >> (((s8 & 3) * 16) + half * 8)) & 0xffu;
            float4 fa = *(const float4*)&f2p[jl];
            float4 fb = *(const float4*)&f2p[jl + 4];
            float fv[8] = {fa.x, fa.y, fa.z, fa.w, fb.x, fb.y, fb.z, fb.w};
            union { f16x2_t h2[4]; f16x8_t v; } ua;
#pragma unroll
            for (int jp = 0; jp < 4; ++jp) {
                float pv[2];
#pragma unroll
                for (int e = 0; e < 2; ++e) {
                    int jj = jp * 2 + e;
                    float t1 = f1v + fv[jj];
                    t1 = fmaxf(t1, 0.2f * t1);
                    pv[e] = (bits8 & (1u << jj))
                          ? __builtin_amdgcn_exp2f(fmaf(t1, LOG2E, negMiL))
                          : 0.f;
                }
                auto pk = __builtin_amdgcn_cvt_pkrtz(pv[0], pv[1]);  // __fp16x2
                ua.h2[jp] = *(f16x2_t*)&pk;                          // bit-pun
            }
            const int gx = (2 * s8 + half) ^ (m32 & 15);
            f16x8_t b0 = *(const f16x8_t*)&whx[w * 8192 + m32 * 128 + (gx << 3)];
            f16x8_t b1 = *(const f16x8_t*)&whx[w * 8192 + (m32 + 32) * 128 + (gx << 3)];
            acc0 = __builtin_amdgcn_mfma_f32_32x32x16_f16(ua.v, b0, acc0, 0, 0, 0);
            acc1 = __builtin_amdgcn_mfma_f32_32x32x16_f16(ua.v, b1, acc1, 0, 0, 0);
            acc2 = __builtin_amdgcn_mfma_f32_32x32x16_f16(ua.v, bones, acc2, 0, 0, 0);
        }
    }

    // ---- block-internal combine: sum 4 wave-partials, divide once, write out
    __syncthreads();                           // all MFMA LDS reads done
    float* F = (float*)whx;                    // [4][32][64] fp32 = 32 KB
    float* Z = (float*)whx + 4 * 32 * 64;      // [4][32]
#pragma unroll
    for (int r = 0; r < 16; ++r) {
        int rr = (r & 3) + 8 * (r >> 2) + 4 * half;   // verified C-layout (m74/m101)
        F[(w * 32 + rr) * 64 + m32] = acc0[r];
        F[(w * 32 + rr) * 64 + m32 + 32] = acc1[r];
        if (m32 == 0) Z[w * 32 + rr] = acc2[r];
    }
    __syncthreads();

    const int orow = t >> 3;        // 0..31
    const int oc = (t & 7) * 8;     // 8-col granule
    float4 s0 = {0.f, 0.f, 0.f, 0.f}, s1 = {0.f, 0.f, 0.f, 0.f};
    float z = 0.f;
#pragma unroll
    for (int ww = 0; ww < 4; ++ww) {
        z += Z[ww * 32 + orow];
        float4 u0 = *(const float4*)&F[(ww * 32 + orow) * 64 + oc];
        float4 u1 = *(const float4*)&F[(ww * 32 + orow) * 64 + oc + 4];
        s0.x += u0.x; s0.y += u0.y; s0.z += u0.z; s0.w += u0.w;
        s1.x += u1.x; s1.y += u1.y; s1.z += u1.z; s1.w += u1.w;
    }
    float zi = 1.f / z;
    s0.x *= zi; s0.y *= zi; s0.z *= zi; s0.w *= zi;
    s1.x *= zi; s1.y *= zi; s1.z *= zi; s1.w *= zi;
    float* op = out + (size_t)(b * NN + I0 + orow) * HID + oc;
    *(float4*)op = s0;
    *(float4*)(op + 4) = s1;
}

extern "C" void kernel_launch(void* const* d_in, const int* in_sizes, int n_in,
                              void* d_out, int out_size, void* d_ws, size_t ws_size,
                              hipStream_t stream)
{
    const float* x = (const float*)d_in[0];
    const int* adj = (const int*)d_in[1];
    const float* W = (const float*)d_in[2];
    const float* a = (const float*)d_in[3];
    float* out = (float*)d_out;
    char* ws = (char*)d_ws;

    _Float16* wht = (_Float16*)(ws);                              // 2 MB
    float* f1   = (float*)(ws + (2u << 20));                      // 64 KB
    float* f2   = (float*)(ws + (2u << 20) + (64u << 10));        // 64 KB
    float* f2mx = (float*)(ws + (2u << 20) + (128u << 10));       // 32 B
    unsigned long long* mbuf = (unsigned long long*)(ws + (3u << 20)); // 4 MB

    hipLaunchKernelGGL(k_prep, dim3(2304), dim3(256), 0, stream,
                       x, W, a, adj, mbuf, wht, f1, f2);
    hipLaunchKernelGGL(k_f2max, dim3(NB), dim3(256), 0, stream, f2, f2mx);
    hipLaunchKernelGGL(k_attn, dim3(512), dim3(256), 0, stream,
                       mbuf, wht, f1, f2, f2mx, out);
}

// Round 4
// 228.092 us; speedup vs baseline: 1.1005x; 1.0147x over previous
//
#include <hip/hip_runtime.h>

#define NB 8
#define NN 2048
#define DIN 256
#define HID 64

typedef _Float16 f16x8_t __attribute__((ext_vector_type(8)));
typedef _Float16 f16x2_t __attribute__((ext_vector_type(2)));
typedef float f32x16_t __attribute__((ext_vector_type(16)));

// ---------------------------------------------------------------------------
// k_prep: fused (wh-role | pack-role).
//   blocks 0..255   : Wh = x@W fp32, f1/f2, WhT fp16 [b][h][n], and a
//                     per-block f2 partial max -> f2part[bid] (replaces the
//                     k_f2max kernel; k_attn reduces 32 partials in-register)
//   blocks 256..2303: adjacency -> 64-bit masks via wave ballot (pack-role)
// ---------------------------------------------------------------------------
__global__ __launch_bounds__(256) void k_prep(
    const float* __restrict__ x, const float* __restrict__ W,
    const float* __restrict__ a, const int* __restrict__ adj,
    unsigned long long* __restrict__ mb, _Float16* __restrict__ wht,
    float* __restrict__ f1, float* __restrict__ f2,
    float* __restrict__ f2part)
{
    __shared__ float smem[DIN * 64];   // 64 KB (wh-role only; reused as T[h][row])
    const int bid = blockIdx.x;
    const int t = threadIdx.x;

    if (bid >= 256) {
        // ---------------- pack-role ----------------
        const int lane = t & 63;
        const int wave = (bid - 256) * 4 + (t >> 6);   // 0..8191
#pragma unroll
        for (int rr = 0; rr < 2; ++rr) {
            const int row = wave * 2 + rr;             // 0..16383 (= b*NN+n)
            const int* ar = adj + (size_t)row * NN;
            unsigned long long myw = 0;
#pragma unroll
            for (int k = 0; k < 32; ++k) {
                unsigned long long bal = __ballot(ar[k * 64 + lane] != 0);
                if ((lane & 31) == k) myw = bal;
            }
            if (lane < 32) mb[(size_t)row * 32 + lane] = myw;
        }
        return;
    }

    // ---------------- wh-role ----------------
    const int g0 = bid * 64;           // global row base (over B*N)
    const int b = g0 >> 11;
    const int n0 = g0 & (NN - 1);

    const float4* x4 = (const float4*)x;
#pragma unroll
    for (int it = 0; it < 16; ++it) {
        int c = t + it * 256;
        int row = c & 63;
        int dg = c >> 6;
        float4 v = x4[(size_t)(g0 + row) * 64 + dg];
        smem[(dg * 4 + 0) * 64 + row] = v.x;
        smem[(dg * 4 + 1) * 64 + row] = v.y;
        smem[(dg * 4 + 2) * 64 + row] = v.z;
        smem[(dg * 4 + 3) * 64 + row] = v.w;
    }
    __syncthreads();

    const int hq = t & 15;   // h-quad: cols hq*4..+3
    const int rg = t >> 4;   // row-group: rows rg*4..+3
    const float4* W4 = (const float4*)W;
    float acc[4][4] = {};
#pragma unroll 8
    for (int d = 0; d < DIN; ++d) {
        float4 wv = W4[d * 16 + hq];
        float4 xv = *(const float4*)&smem[d * 64 + rg * 4];
        float xr[4] = {xv.x, xv.y, xv.z, xv.w};
        float wk[4] = {wv.x, wv.y, wv.z, wv.w};
#pragma unroll
        for (int r = 0; r < 4; ++r)
#pragma unroll
            for (int k = 0; k < 4; ++k) acc[r][k] += xr[r] * wk[k];
    }

    // f1/f2: reduce over h (16 hq-lanes per row-group; xor<16 stays in group)
    float4 a1v = ((const float4*)a)[hq];
    float4 a2v = ((const float4*)a)[16 + hq];
    float mx2 = -3.4e38f;
#pragma unroll
    for (int r = 0; r < 4; ++r) {
        float p1 = acc[r][0] * a1v.x + acc[r][1] * a1v.y + acc[r][2] * a1v.z + acc[r][3] * a1v.w;
        float p2 = acc[r][0] * a2v.x + acc[r][1] * a2v.y + acc[r][2] * a2v.z + acc[r][3] * a2v.w;
#pragma unroll
        for (int m = 1; m < 16; m <<= 1) {
            p1 += __shfl_xor(p1, m);
            p2 += __shfl_xor(p2, m);
        }
        if (hq == 0) {
            f1[g0 + rg * 4 + r] = p1;
            f2[g0 + rg * 4 + r] = p2;
        }
        mx2 = fmaxf(mx2, p2);
    }
    // per-wave max (p2 uniform across hq lanes; rg spans bits 4..5 of lane)
    mx2 = fmaxf(mx2, __shfl_xor(mx2, 16));
    mx2 = fmaxf(mx2, __shfl_xor(mx2, 32));
    if ((t & 63) == 0) smem[8192 + (t >> 6)] = mx2;   // x-staging region is dead

    __syncthreads();
    if (t == 0)
        f2part[bid] = fmaxf(fmaxf(smem[8192], smem[8193]),
                            fmaxf(smem[8194], smem[8195]));
    // transpose: T[h][row], 4-row groups XOR-swizzled to break bank conflicts
    // (writes land in smem[0..4095]; no overlap with smem[8192..8195])
#pragma unroll
    for (int r = 0; r < 4; ++r)
#pragma unroll
        for (int k = 0; k < 4; ++k) {
            int h = hq * 4 + k;
            int row = rg * 4 + r;
            smem[h * 64 + (((row >> 2) ^ (h & 15)) << 2) + (row & 3)] = acc[r][k];
        }
    __syncthreads();

    const int h = t >> 2;    // 0..63
    const int rc = t & 3;    // 16-row chunk
    union { _Float16 fh[16]; uint4 u4[2]; } uh;
#pragma unroll
    for (int q = 0; q < 4; ++q) {
        float4 v = *(const float4*)&smem[h * 64 + (((rc * 4 + q) ^ (h & 15)) << 2)];
        uh.fh[q * 4 + 0] = (_Float16)v.x;
        uh.fh[q * 4 + 1] = (_Float16)v.y;
        uh.fh[q * 4 + 2] = (_Float16)v.z;
        uh.fh[q * 4 + 3] = (_Float16)v.w;
    }
    size_t obase = (size_t)(b * HID + h) * NN + n0 + rc * 16;
    *(uint4*)&wht[obase] = uh.u4[0];
    *(uint4*)&wht[obase + 8] = uh.u4[1];
}

// ---------------------------------------------------------------------------
// k_attn: masked-softmax + P@Wh, FULL J per block. 512 blocks = (b, 32-row
// tile); 4 waves, wave w owns j-quarter [w*512,+512). Per sync round: stage
// 4x128-j Wh chunks (64 KB LDS), 8 MFMA steps each. Block-internal combine,
// single divide, direct fp32 out. f2max[b] recomputed in-register from the
// 32 per-block partials (1 load + 5 shfl) — no k_f2max kernel.
// ---------------------------------------------------------------------------
__global__ __launch_bounds__(256) void k_attn(
    const unsigned long long* __restrict__ mb, const _Float16* __restrict__ wht,
    const float* __restrict__ f1, const float* __restrict__ f2,
    const float* __restrict__ f2part,
    float* __restrict__ out)
{
    __shared__ _Float16 whx[4 * 64 * 128];   // 64 KB: [slab][h][j128], XOR-swizzled
    const int t = threadIdx.x;
    const int w = t >> 6, lane = t & 63;
    const int bx = blockIdx.x;
    const int it = bx & 63;
    const int b = bx >> 6;
    const int I0 = it * 32;
    const int half = lane >> 5;
    const int m32 = lane & 31;
    const int row = I0 + m32;
    const int jq0 = w * 512;           // this wave's j-quarter base

    // f2max[b] from 32 partials: both 32-lane halves load the same set
    float f2b = f2part[b * 32 + m32];
#pragma unroll
    for (int s = 1; s < 32; s <<= 1) f2b = fmaxf(f2b, __shfl_xor(f2b, s));

    const float f1v = f1[b * NN + row];
    float Mi = f1v + f2b;
    Mi = Mi > 0.f ? Mi : 0.2f * Mi;            // lrelu monotone -> valid bound
    const float LOG2E = 1.4426950408889634f;
    const float negMiL = -Mi * LOG2E;
    const float* f2p = f2 + b * NN;

    // this row's 8 mask words (j in [jq0, jq0+512))
    const unsigned long long* mrow = mb + (size_t)(b * NN + row) * 32 + w * 8;
    unsigned long long m[8];
#pragma unroll
    for (int q = 0; q < 4; ++q) {
        ulonglong2 qq = *(const ulonglong2*)(mrow + q * 2);
        m[q * 2] = qq.x; m[q * 2 + 1] = qq.y;
    }

    f16x8_t bones;
#pragma unroll
    for (int i = 0; i < 8; ++i) bones[i] = (_Float16)1.0f;

    f32x16_t acc0, acc1, acc2;
#pragma unroll
    for (int i = 0; i < 16; ++i) { acc0[i] = 0.f; acc1[i] = 0.f; acc2[i] = 0.f; }

    for (int s = 0; s < 4; ++s) {
        if (s) __syncthreads();
        // stage: 4 slabs x 64 h x 128 j  (64 KB), coalesced uint4
#pragma unroll
        for (int cc = 0; cc < 16; ++cc) {
            int id = t + cc * 256;
            int g = id & 15;
            int h = (id >> 4) & 63;
            int slab = id >> 10;
            int gp = g ^ (h & 15);
            size_t src = (size_t)(b * HID + h) * NN + slab * 512 + s * 128 + g * 8;
            *(uint4*)&whx[slab * 8192 + h * 128 + gp * 8] = *(const uint4*)&wht[src];
        }
        __syncthreads();
#pragma unroll
        for (int s8 = 0; s8 < 8; ++s8) {
            const int jl = jq0 + s * 128 + s8 * 16 + half * 8;   // lane's 8-j group
            const uint32_t bits8 =
                (uint32_t)(m[s * 2 + (s8 >> 2)] >> (((s8 & 3) * 16) + half * 8)) & 0xffu;
            float4 fa = *(const float4*)&f2p[jl];
            float4 fb = *(const float4*)&f2p[jl + 4];
            float fv[8] = {fa.x, fa.y, fa.z, fa.w, fb.x, fb.y, fb.z, fb.w};
            union { f16x2_t h2[4]; f16x8_t v; } ua;
#pragma unroll
            for (int jp = 0; jp < 4; ++jp) {
                float pv[2];
#pragma unroll
                for (int e = 0; e < 2; ++e) {
                    int jj = jp * 2 + e;
                    float t1 = f1v + fv[jj];
                    t1 = fmaxf(t1, 0.2f * t1);
                    pv[e] = (bits8 & (1u << jj))
                          ? __builtin_amdgcn_exp2f(fmaf(t1, LOG2E, negMiL))
                          : 0.f;
                }
                auto pk = __builtin_amdgcn_cvt_pkrtz(pv[0], pv[1]);  // __fp16x2
                ua.h2[jp] = *(f16x2_t*)&pk;                          // bit-pun
            }
            const int gx = (2 * s8 + half) ^ (m32 & 15);
            f16x8_t b0 = *(const f16x8_t*)&whx[w * 8192 + m32 * 128 + (gx << 3)];
            f16x8_t b1 = *(const f16x8_t*)&whx[w * 8192 + (m32 + 32) * 128 + (gx << 3)];
            acc0 = __builtin_amdgcn_mfma_f32_32x32x16_f16(ua.v, b0, acc0, 0, 0, 0);
            acc1 = __builtin_amdgcn_mfma_f32_32x32x16_f16(ua.v, b1, acc1, 0, 0, 0);
            acc2 = __builtin_amdgcn_mfma_f32_32x32x16_f16(ua.v, bones, acc2, 0, 0, 0);
        }
    }

    // ---- block-internal combine: sum 4 wave-partials, divide once, write out
    __syncthreads();                           // all MFMA LDS reads done
    float* F = (float*)whx;                    // [4][32][64] fp32 = 32 KB
    float* Z = (float*)whx + 4 * 32 * 64;      // [4][32]
#pragma unroll
    for (int r = 0; r < 16; ++r) {
        int rr = (r & 3) + 8 * (r >> 2) + 4 * half;   // verified C-layout (m74/m101)
        F[(w * 32 + rr) * 64 + m32] = acc0[r];
        F[(w * 32 + rr) * 64 + m32 + 32] = acc1[r];
        if (m32 == 0) Z[w * 32 + rr] = acc2[r];
    }
    __syncthreads();

    const int orow = t >> 3;        // 0..31
    const int oc = (t & 7) * 8;     // 8-col granule
    float4 s0 = {0.f, 0.f, 0.f, 0.f}, s1 = {0.f, 0.f, 0.f, 0.f};
    float z = 0.f;
#pragma unroll
    for (int ww = 0; ww < 4; ++ww) {
        z += Z[ww * 32 + orow];
        float4 u0 = *(const float4*)&F[(ww * 32 + orow) * 64 + oc];
        float4 u1 = *(const float4*)&F[(ww * 32 + orow) * 64 + oc + 4];
        s0.x += u0.x; s0.y += u0.y; s0.z += u0.z; s0.w += u0.w;
        s1.x += u1.x; s1.y += u1.y; s1.z += u1.z; s1.w += u1.w;
    }
    float zi = 1.f / z;
    s0.x *= zi; s0.y *= zi; s0.z *= zi; s0.w *= zi;
    s1.x *= zi; s1.y *= zi; s1.z *= zi; s1.w *= zi;
    float* op = out + (size_t)(b * NN + I0 + orow) * HID + oc;
    *(float4*)op = s0;
    *(float4*)(op + 4) = s1;
}

extern "C" void kernel_launch(void* const* d_in, const int* in_sizes, int n_in,
                              void* d_out, int out_size, void* d_ws, size_t ws_size,
                              hipStream_t stream)
{
    const float* x = (const float*)d_in[0];
    const int* adj = (const int*)d_in[1];
    const float* W = (const float*)d_in[2];
    const float* a = (const float*)d_in[3];
    float* out = (float*)d_out;
    char* ws = (char*)d_ws;

    _Float16* wht = (_Float16*)(ws);                              // 2 MB
    float* f1     = (float*)(ws + (2u << 20));                    // 64 KB
    float* f2     = (float*)(ws + (2u << 20) + (64u << 10));      // 64 KB
    float* f2part = (float*)(ws + (2u << 20) + (128u << 10));     // 1 KB
    unsigned long long* mbuf = (unsigned long long*)(ws + (3u << 20)); // 4 MB

    hipLaunchKernelGGL(k_prep, dim3(2304), dim3(256), 0, stream,
                       x, W, a, adj, mbuf, wht, f1, f2, f2part);
    hipLaunchKernelGGL(k_attn, dim3(512), dim3(256), 0, stream,
                       mbuf, wht, f1, f2, f2part, out);
}